// Round 3
// baseline (1418.222 us; speedup 1.0000x reference)
//
#include <hip/hip_runtime.h>
#include <hip/hip_bf16.h>
#include <math.h>

// ---------------------------------------------------------------------------
// AdditiveTokenMixer (VMamba-ish): full fp32 implementation.
// B=2, C=256, H=W=48, L=2304, DI=512, NS=DR=16, K=4 directions.
// Layout convention: all activations pixel-major [b, l, ch] (coalesced over ch).
// Scan: chunked linear recurrence (48 chunks x 48 steps, 3 passes).
// ---------------------------------------------------------------------------

constexpr int Bb  = 2;
constexpr int Cc  = 256;
constexpr int Hh  = 48;
constexpr int Wd  = 48;
constexpr int Ll  = Hh * Wd;     // 2304
constexpr int DI  = 512;
constexpr int NS  = 16;
constexpr int DR  = 16;
constexpr int Kd4 = 4;
constexpr int NC  = 48;          // number of chunks
constexpr int CL  = 48;          // chunk length (NC*CL == Ll)

#define DEV __device__ __forceinline__

DEV float sigmoidf_(float x) { return 1.0f / (1.0f + __expf(-x)); }
DEV float siluf_(float x)    { return x * sigmoidf_(x); }
DEV float softplusf_(float x){ return fmaxf(x, 0.0f) + log1pf(__expf(-fabsf(x))); }

// ---------------------------------------------------------------------------
// Transpose x [b, c, l] -> xT [b, l, c]   (tile 32x32 via LDS)
// grid (Ll/32, Cc/32, Bb), block 256
// ---------------------------------------------------------------------------
__global__ __launch_bounds__(256) void transpose_in(const float* __restrict__ x,
                                                    float* __restrict__ xT)
{
    __shared__ float tile[32][33];
    int l0 = blockIdx.x * 32, c0 = blockIdx.y * 32, b = blockIdx.z;
    int t = threadIdx.x;
    int li = t & 31, ci = t >> 5;           // ci 0..7
#pragma unroll
    for (int i = 0; i < 4; i++) {
        int cc = ci + i * 8;
        tile[cc][li] = x[((size_t)b * Cc + c0 + cc) * Ll + l0 + li];
    }
    __syncthreads();
#pragma unroll
    for (int i = 0; i < 4; i++) {
        int ll = ci + i * 8;
        xT[((size_t)b * Ll + l0 + ll) * Cc + c0 + li] = tile[li][ll];
    }
}

// ---------------------------------------------------------------------------
// 13x13 depthwise conv, pad 6.  in/out pixel-major [b,l,256].
// grid (Ll, Bb), block 256 (c)
// ---------------------------------------------------------------------------
__global__ __launch_bounds__(256) void dwconv13(const float* __restrict__ xT,
                                                const float* __restrict__ wgt,
                                                const float* __restrict__ bias,
                                                float* __restrict__ out)
{
    int l = blockIdx.x, b = blockIdx.y;
    int h = l / Wd, w = l % Wd, c = threadIdx.x;
    float acc = bias[c];
    const float* wc = wgt + (size_t)c * 169;
    for (int ky = 0; ky < 13; ky++) {
        int y = h + ky - 6;
        if ((unsigned)y >= (unsigned)Hh) continue;
        const float* row = xT + ((size_t)b * Ll + y * Wd) * Cc;
        for (int kx = 0; kx < 13; kx++) {
            int xx = w + kx - 6;
            if ((unsigned)xx >= (unsigned)Wd) continue;
            acc = fmaf(row[(size_t)xx * Cc + c], wc[ky * 13 + kx], acc);
        }
    }
    out[((size_t)b * Ll + l) * Cc + c] = acc;
}

// ---------------------------------------------------------------------------
// Generic fp32 GEMM: C[m,n] = sum_k A[m,k]*W[n,k]; M%64==0, N%64==0, K%16==0.
// act: 0 none, 1 clip(0,6).  block 256, tile 64x64x16, 4x4 per thread.
// ---------------------------------------------------------------------------
__global__ __launch_bounds__(256) void gemm_aw(const float* __restrict__ A, int lda,
                                               const float* __restrict__ W, int ldw,
                                               float* __restrict__ C, int ldc,
                                               int M, int N, int Kdim, int act)
{
    __shared__ float As[16][68];
    __shared__ float Ws[16][68];
    int bm = blockIdx.x * 64, bn = blockIdx.y * 64;
    int t = threadIdx.x;
    int lm = t >> 2;             // 0..63
    int lk = (t & 3) * 4;        // 0,4,8,12
    int tn = (t & 15) * 4, tm = (t >> 4) * 4;
    float acc[4][4] = {};
    for (int k0 = 0; k0 < Kdim; k0 += 16) {
        float4 av = *(const float4*)(A + (size_t)(bm + lm) * lda + k0 + lk);
        float4 wv = *(const float4*)(W + (size_t)(bn + lm) * ldw + k0 + lk);
        As[lk + 0][lm] = av.x; As[lk + 1][lm] = av.y; As[lk + 2][lm] = av.z; As[lk + 3][lm] = av.w;
        Ws[lk + 0][lm] = wv.x; Ws[lk + 1][lm] = wv.y; Ws[lk + 2][lm] = wv.z; Ws[lk + 3][lm] = wv.w;
        __syncthreads();
#pragma unroll
        for (int kk = 0; kk < 16; kk++) {
            float a[4], w4[4];
#pragma unroll
            for (int i = 0; i < 4; i++) a[i] = As[kk][tm + i];
#pragma unroll
            for (int j = 0; j < 4; j++) w4[j] = Ws[kk][tn + j];
#pragma unroll
            for (int i = 0; i < 4; i++)
#pragma unroll
                for (int j = 0; j < 4; j++)
                    acc[i][j] = fmaf(a[i], w4[j], acc[i][j]);
        }
        __syncthreads();
    }
#pragma unroll
    for (int i = 0; i < 4; i++)
#pragma unroll
        for (int j = 0; j < 4; j++) {
            float v = acc[i][j];
            if (act == 1) v = fminf(fmaxf(v, 0.0f), 6.0f);
            C[(size_t)(bm + tm + i) * ldc + bn + tn + j] = v;
        }
}

// ---------------------------------------------------------------------------
// dw3x3 + SiLU on xi (cols 0..511 of xz [b,l,1024]); writes x1 (hw order) and
// x2 (wh order), both [b,l,512].  grid (Ll, Bb), block 512
// ---------------------------------------------------------------------------
__global__ __launch_bounds__(512) void conv3_silu_dual(const float* __restrict__ xz,
                                                       const float* __restrict__ cw,
                                                       const float* __restrict__ cb,
                                                       float* __restrict__ x1p,
                                                       float* __restrict__ x2p)
{
    __shared__ float wsm[DI * 9];
    int l = blockIdx.x, b = blockIdx.y;
    int h = l / Wd, w = l % Wd, d = threadIdx.x;
    for (int i = d; i < DI * 9; i += 512) wsm[i] = cw[i];
    __syncthreads();
    float acc = cb[d];
    const float* wp = wsm + d * 9;
#pragma unroll
    for (int ky = 0; ky < 3; ky++) {
        int y = h + ky - 1;
        if ((unsigned)y >= (unsigned)Hh) continue;
#pragma unroll
        for (int kx = 0; kx < 3; kx++) {
            int xx = w + kx - 1;
            if ((unsigned)xx >= (unsigned)Wd) continue;
            acc = fmaf(xz[((size_t)b * Ll + y * Wd + xx) * 1024 + d], wp[ky * 3 + kx], acc);
        }
    }
    float s = siluf_(acc);
    x1p[((size_t)b * Ll + l) * DI + d] = s;
    x2p[((size_t)b * Ll + (w * Hh + h)) * DI + d] = s;
}

// ---------------------------------------------------------------------------
// x_dbl GEMM: for z=(b*4+k): C[l, c(48)] = sum_d xbase_k[b,l,d] * xp[k,c,d]
// grid (Ll/64, 1, 8), block 256; tile 64x48x16, 4x3 per thread
// ---------------------------------------------------------------------------
__global__ __launch_bounds__(256) void gemm_xdbl(const float* __restrict__ x1p,
                                                 const float* __restrict__ x2p,
                                                 const float* __restrict__ xp,
                                                 float* __restrict__ xdbl)
{
    __shared__ float As[16][68];
    __shared__ float Ws[16][52];
    int z = blockIdx.z;
    int b = z >> 2, k = z & 3;
    const float* A = ((k & 1) ? x2p : x1p) + (size_t)b * Ll * DI;
    const float* W = xp + (size_t)k * 48 * DI;
    float* C = xdbl + (size_t)z * Ll * 48;
    int bm = blockIdx.x * 64;
    int t = threadIdx.x;
    int lm = t >> 2, lk = (t & 3) * 4;
    int tn = (t & 15) * 3, tm = (t >> 4) * 4;
    float acc[4][3] = {};
    for (int k0 = 0; k0 < DI; k0 += 16) {
        float4 av = *(const float4*)(A + (size_t)(bm + lm) * DI + k0 + lk);
        As[lk + 0][lm] = av.x; As[lk + 1][lm] = av.y; As[lk + 2][lm] = av.z; As[lk + 3][lm] = av.w;
        if (t < 192) {
            int wn = t >> 2;   // 0..47
            float4 wv = *(const float4*)(W + (size_t)wn * DI + k0 + lk);
            Ws[lk + 0][wn] = wv.x; Ws[lk + 1][wn] = wv.y; Ws[lk + 2][wn] = wv.z; Ws[lk + 3][wn] = wv.w;
        }
        __syncthreads();
#pragma unroll
        for (int kk = 0; kk < 16; kk++) {
            float a[4], w4[3];
#pragma unroll
            for (int i = 0; i < 4; i++) a[i] = As[kk][tm + i];
#pragma unroll
            for (int j = 0; j < 3; j++) w4[j] = Ws[kk][tn + j];
#pragma unroll
            for (int i = 0; i < 4; i++)
#pragma unroll
                for (int j = 0; j < 3; j++)
                    acc[i][j] = fmaf(a[i], w4[j], acc[i][j]);
        }
        __syncthreads();
    }
#pragma unroll
    for (int i = 0; i < 4; i++)
#pragma unroll
        for (int j = 0; j < 3; j++)
            C[(size_t)(bm + tm + i) * 48 + tn + j] = acc[i][j];
}

// ---------------------------------------------------------------------------
// Scan pass A: per (chunk, b, k, d) compute chunk summary (P,Q):
//   h_end = P*h_in + Q  for each of 16 states.
// grid (NC, Bb*Kd4), block 512 (=d)
// ---------------------------------------------------------------------------
__global__ __launch_bounds__(512) void scan_passA(const float* __restrict__ xdbl,
                                                  const float* __restrict__ x1p,
                                                  const float* __restrict__ x2p,
                                                  const float* __restrict__ dtw,
                                                  const float* __restrict__ dtb,
                                                  const float* __restrict__ al,
                                                  float* __restrict__ P,
                                                  float* __restrict__ Q)
{
    __shared__ __align__(16) float xds[CL * 48];
    int chunk = blockIdx.x;
    int bk = blockIdx.y;
    int b = bk >> 2, k = bk & 3;
    int d = threadIdx.x;
    int rowbase = (k < 2) ? chunk * CL : (Ll - CL * (chunk + 1));
    const float* src = xdbl + ((size_t)bk * Ll + rowbase) * 48;
    for (int i = d; i < CL * 48; i += 512) xds[i] = src[i];

    float w_dt[16], Aa[16];
    const float* dtwp = dtw + ((size_t)k * DI + d) * DR;
    const float* alp  = al  + ((size_t)k * DI + d) * NS;
#pragma unroll
    for (int n = 0; n < 16; n++) { w_dt[n] = dtwp[n]; Aa[n] = -__expf(alp[n]); }
    float dtb_s = dtb[k * DI + d];
    const float* xb = ((k & 1) ? x2p : x1p) + (size_t)b * Ll * DI + d;

    float Pr[16], Qr[16];
#pragma unroll
    for (int n = 0; n < 16; n++) { Pr[n] = 1.0f; Qr[n] = 0.0f; }
    __syncthreads();

    for (int tl = 0; tl < CL; tl++) {
        int tglob = chunk * CL + tl;
        int p  = (k < 2) ? tglob : (Ll - 1 - tglob);
        int rl = (k < 2) ? tl : (CL - 1 - tl);
        float xv[32];
        {
            const float4* xr4 = reinterpret_cast<const float4*>(&xds[rl * 48]);
#pragma unroll
            for (int i = 0; i < 8; i++) {
                float4 q = xr4[i];
                xv[4 * i + 0] = q.x; xv[4 * i + 1] = q.y; xv[4 * i + 2] = q.z; xv[4 * i + 3] = q.w;
            }
        }
        float u = xb[(size_t)p * DI];
        float dt = dtb_s;
#pragma unroll
        for (int r = 0; r < 16; r++) dt = fmaf(w_dt[r], xv[r], dt);
        dt = softplusf_(dt);
        float du = dt * u;
#pragma unroll
        for (int n = 0; n < 16; n++) {
            float a = __expf(dt * Aa[n]);
            Pr[n] *= a;
            Qr[n] = fmaf(a, Qr[n], du * xv[16 + n]);
        }
    }
    size_t obase = ((size_t)bk * NC + chunk) * NS * DI + d;
#pragma unroll
    for (int n = 0; n < 16; n++) {
        P[obase + (size_t)n * DI] = Pr[n];
        Q[obase + (size_t)n * DI] = Qr[n];
    }
}

// ---------------------------------------------------------------------------
// Scan pass B: sequential scan over chunk summaries -> h_in per chunk.
// flat threads over (bk, n, d); grid 128 x block 512
// ---------------------------------------------------------------------------
__global__ __launch_bounds__(512) void scan_passB(const float* __restrict__ P,
                                                  const float* __restrict__ Q,
                                                  float* __restrict__ hin)
{
    int gid = blockIdx.x * 512 + threadIdx.x;
    int d = gid & (DI - 1);
    int n = (gid >> 9) & 15;
    int bk = gid >> 13;
    float h = 0.0f;
    for (int c = 0; c < NC; c++) {
        size_t idx = (((size_t)bk * NC + c) * NS + n) * DI + d;
        hin[idx] = h;
        h = fmaf(P[idx], h, Q[idx]);
    }
}

// ---------------------------------------------------------------------------
// Scan pass C: replay each chunk with known h_in, emit ys (+ D skip).
// ys stored source-pixel-indexed: ysA[(bk*L + p)*DI + d]
// ---------------------------------------------------------------------------
__global__ __launch_bounds__(512) void scan_passC(const float* __restrict__ xdbl,
                                                  const float* __restrict__ x1p,
                                                  const float* __restrict__ x2p,
                                                  const float* __restrict__ dtw,
                                                  const float* __restrict__ dtb,
                                                  const float* __restrict__ al,
                                                  const float* __restrict__ dsk,
                                                  const float* __restrict__ hin,
                                                  float* __restrict__ ysA)
{
    __shared__ __align__(16) float xds[CL * 48];
    int chunk = blockIdx.x;
    int bk = blockIdx.y;
    int b = bk >> 2, k = bk & 3;
    int d = threadIdx.x;
    int rowbase = (k < 2) ? chunk * CL : (Ll - CL * (chunk + 1));
    const float* src = xdbl + ((size_t)bk * Ll + rowbase) * 48;
    for (int i = d; i < CL * 48; i += 512) xds[i] = src[i];

    float w_dt[16], Aa[16], hreg[16];
    const float* dtwp = dtw + ((size_t)k * DI + d) * DR;
    const float* alp  = al  + ((size_t)k * DI + d) * NS;
#pragma unroll
    for (int n = 0; n < 16; n++) { w_dt[n] = dtwp[n]; Aa[n] = -__expf(alp[n]); }
    float dtb_s = dtb[k * DI + d];
    float dp_s  = dsk[k * DI + d];
    size_t hbase = ((size_t)bk * NC + chunk) * NS * DI + d;
#pragma unroll
    for (int n = 0; n < 16; n++) hreg[n] = hin[hbase + (size_t)n * DI];
    const float* xb = ((k & 1) ? x2p : x1p) + (size_t)b * Ll * DI + d;
    __syncthreads();

    for (int tl = 0; tl < CL; tl++) {
        int tglob = chunk * CL + tl;
        int p  = (k < 2) ? tglob : (Ll - 1 - tglob);
        int rl = (k < 2) ? tl : (CL - 1 - tl);
        float xv[48];
        {
            const float4* xr4 = reinterpret_cast<const float4*>(&xds[rl * 48]);
#pragma unroll
            for (int i = 0; i < 12; i++) {
                float4 q = xr4[i];
                xv[4 * i + 0] = q.x; xv[4 * i + 1] = q.y; xv[4 * i + 2] = q.z; xv[4 * i + 3] = q.w;
            }
        }
        float u = xb[(size_t)p * DI];
        float dt = dtb_s;
#pragma unroll
        for (int r = 0; r < 16; r++) dt = fmaf(w_dt[r], xv[r], dt);
        dt = softplusf_(dt);
        float du = dt * u;
        float y = 0.0f;
#pragma unroll
        for (int n = 0; n < 16; n++) {
            float a = __expf(dt * Aa[n]);
            hreg[n] = fmaf(a, hreg[n], du * xv[16 + n]);
            y = fmaf(hreg[n], xv[32 + n], y);
        }
        y = fmaf(dp_s, u, y);
        ysA[((size_t)bk * Ll + p) * DI + d] = y;
    }
}

// ---------------------------------------------------------------------------
// Combine 4 directions + LayerNorm(512) + SiLU(z) gate -> yln [b,l,512]
// grid (Ll, Bb), block 512
// ---------------------------------------------------------------------------
__global__ __launch_bounds__(512) void combine_ln(const float* __restrict__ ysA,
                                                  const float* __restrict__ xz,
                                                  const float* __restrict__ lnw,
                                                  const float* __restrict__ lnb,
                                                  float* __restrict__ yln)
{
    __shared__ float red[16];
    int l = blockIdx.x, b = blockIdx.y;
    int h = l / Wd, w = l % Wd;
    int wh = w * Hh + h;
    int d = threadIdx.x;
    size_t k0 = ((size_t)(b * 4 + 0) * Ll + l)  * DI + d;
    size_t k1 = ((size_t)(b * 4 + 1) * Ll + wh) * DI + d;
    size_t k2 = ((size_t)(b * 4 + 2) * Ll + l)  * DI + d;
    size_t k3 = ((size_t)(b * 4 + 3) * Ll + wh) * DI + d;
    float v = ysA[k0] + ysA[k1] + ysA[k2] + ysA[k3];

    float s = v, s2 = v * v;
#pragma unroll
    for (int off = 32; off > 0; off >>= 1) {
        s  += __shfl_down(s, off);
        s2 += __shfl_down(s2, off);
    }
    int wid = d >> 6, lane = d & 63;
    if (lane == 0) { red[wid] = s; red[8 + wid] = s2; }
    __syncthreads();
    if (d == 0) {
        float ts = 0.0f, ts2 = 0.0f;
        for (int i = 0; i < 8; i++) { ts += red[i]; ts2 += red[8 + i]; }
        red[0] = ts * (1.0f / DI);
        red[1] = ts2 * (1.0f / DI);
    }
    __syncthreads();
    float mu = red[0];
    float var = red[1] - mu * mu;
    float yn = (v - mu) * rsqrtf(var + 1e-5f) * lnw[d] + lnb[d];
    float zv = xz[((size_t)b * Ll + l) * 1024 + DI + d];
    yn *= siluf_(zv);
    yln[((size_t)b * Ll + l) * DI + d] = yn;
}

// ---------------------------------------------------------------------------
// conv_qk: qc = dw3(q)+qb, kc = dw3(k)+kb, sbuf = qc+kc   [b,l,256]
// ---------------------------------------------------------------------------
__global__ __launch_bounds__(256) void conv_qk(const float* __restrict__ qkv,
                                               const float* __restrict__ qw,
                                               const float* __restrict__ qb,
                                               const float* __restrict__ kw,
                                               const float* __restrict__ kb,
                                               float* __restrict__ sbuf)
{
    __shared__ float wq[Cc * 9], wk[Cc * 9];
    int l = blockIdx.x, b = blockIdx.y;
    int h = l / Wd, w = l % Wd, c = threadIdx.x;
    for (int i = c; i < Cc * 9; i += 256) { wq[i] = qw[i]; wk[i] = kw[i]; }
    __syncthreads();
    float aq = qb[c], ak = kb[c];
#pragma unroll
    for (int ky = 0; ky < 3; ky++) {
        int y = h + ky - 1;
        if ((unsigned)y >= (unsigned)Hh) continue;
#pragma unroll
        for (int kx = 0; kx < 3; kx++) {
            int xx = w + kx - 1;
            if ((unsigned)xx >= (unsigned)Wd) continue;
            size_t base = ((size_t)b * Ll + y * Wd + xx) * 768;
            aq = fmaf(qkv[base + c],       wq[c * 9 + ky * 3 + kx], aq);
            ak = fmaf(qkv[base + Cc + c],  wk[c * 9 + ky * 3 + kx], ak);
        }
    }
    sbuf[((size_t)b * Ll + l) * Cc + c] = aq + ak;
}

// ---------------------------------------------------------------------------
// conv_g: g = (dw3(sbuf)+db) * v     [b,l,256]
// ---------------------------------------------------------------------------
__global__ __launch_bounds__(256) void conv_g(const float* __restrict__ sbuf,
                                              const float* __restrict__ dw,
                                              const float* __restrict__ db,
                                              const float* __restrict__ qkv,
                                              float* __restrict__ g)
{
    __shared__ float wsm[Cc * 9];
    int l = blockIdx.x, b = blockIdx.y;
    int h = l / Wd, w = l % Wd, c = threadIdx.x;
    for (int i = c; i < Cc * 9; i += 256) wsm[i] = dw[i];
    __syncthreads();
    float acc = db[c];
#pragma unroll
    for (int ky = 0; ky < 3; ky++) {
        int y = h + ky - 1;
        if ((unsigned)y >= (unsigned)Hh) continue;
#pragma unroll
        for (int kx = 0; kx < 3; kx++) {
            int xx = w + kx - 1;
            if ((unsigned)xx >= (unsigned)Wd) continue;
            acc = fmaf(sbuf[((size_t)b * Ll + y * Wd + xx) * Cc + c], wsm[c * 9 + ky * 3 + kx], acc);
        }
    }
    float v = qkv[((size_t)b * Ll + l) * 768 + 2 * Cc + c];
    g[((size_t)b * Ll + l) * Cc + c] = acc * v;
}

// ---------------------------------------------------------------------------
// reduce_mean: partial sums of g over pixels (atomic accumulate)
// grid (18, Bb) block 256; each block sums 128 pixels
// ---------------------------------------------------------------------------
__global__ __launch_bounds__(256) void reduce_mean(const float* __restrict__ g,
                                                   float* __restrict__ m)
{
    int b = blockIdx.y, c = threadIdx.x;
    int l0 = blockIdx.x * 128;
    float s = 0.0f;
    for (int i = 0; i < 128; i++)
        s += g[((size_t)b * Ll + l0 + i) * Cc + c];
    atomicAdd(&m[b * Cc + c], s);
}

// ---------------------------------------------------------------------------
// cbr: y1[b,o] = relu( (sum_c mean_g[c]*w[o,c]) * gain[o] + bias[o] )
// ---------------------------------------------------------------------------
__global__ __launch_bounds__(256) void cbr_kernel(const float* __restrict__ m,
                                                  const float* __restrict__ wgt,
                                                  const float* __restrict__ gain,
                                                  const float* __restrict__ bias,
                                                  float* __restrict__ y1)
{
    __shared__ float ms[Cc];
    int b = blockIdx.x, o = threadIdx.x;
    ms[o] = m[b * Cc + o] * (1.0f / (float)Ll);
    __syncthreads();
    float t = 0.0f;
    for (int c = 0; c < Cc; c++) t = fmaf(ms[c], wgt[(size_t)o * Cc + c], t);
    float v = t * gain[o] + bias[o];
    y1[b * Cc + o] = fmaxf(v, 0.0f);
}

// ---------------------------------------------------------------------------
// final: out[b,o,l] = g[b,l,o] * (y1[b,o] + y2[b,l,o])   (transpose via LDS)
// grid (Ll/32, Cc/32, Bb), block 256
// ---------------------------------------------------------------------------
__global__ __launch_bounds__(256) void final_kernel(const float* __restrict__ g,
                                                    const float* __restrict__ y1,
                                                    const float* __restrict__ y2,
                                                    float* __restrict__ out)
{
    __shared__ float tile[32][33];
    int l0 = blockIdx.x * 32, o0 = blockIdx.y * 32, b = blockIdx.z;
    int t = threadIdx.x;
    int lo = t & 31, li = t >> 5;
#pragma unroll
    for (int i = 0; i < 4; i++) {
        int ll = li + i * 8;
        size_t idx = ((size_t)b * Ll + l0 + ll) * Cc + o0 + lo;
        tile[ll][lo] = g[idx] * (y1[b * Cc + o0 + lo] + y2[idx]);
    }
    __syncthreads();
#pragma unroll
    for (int i = 0; i < 4; i++) {
        int oo = li + i * 8;
        out[((size_t)b * Cc + o0 + oo) * Ll + l0 + lo] = tile[lo][oo];
    }
}

// ---------------------------------------------------------------------------
// Host side
// ---------------------------------------------------------------------------
struct SSParams {
    const float *in_w, *cw, *cb, *xp, *dtw, *dtb, *al, *dsk, *lnw, *lnb, *ow;
};

static void run_ss2d(const float* inp, const SSParams& p, float* outp, int act,
                     float* xz, float* x1p, float* x2p, float* xdbl,
                     float* Pb, float* Qb, float* hinb, float* ysA, float* yln,
                     hipStream_t stream)
{
    const int Mrows = Bb * Ll;   // 4608
    gemm_aw<<<dim3(Mrows / 64, 1024 / 64), 256, 0, stream>>>(inp, Cc, p.in_w, Cc, xz, 1024,
                                                             Mrows, 1024, Cc, 0);
    conv3_silu_dual<<<dim3(Ll, Bb), 512, 0, stream>>>(xz, p.cw, p.cb, x1p, x2p);
    gemm_xdbl<<<dim3(Ll / 64, 1, Bb * Kd4), 256, 0, stream>>>(x1p, x2p, p.xp, xdbl);
    scan_passA<<<dim3(NC, Bb * Kd4), 512, 0, stream>>>(xdbl, x1p, x2p, p.dtw, p.dtb, p.al, Pb, Qb);
    scan_passB<<<dim3((Bb * Kd4 * NS * DI) / 512), 512, 0, stream>>>(Pb, Qb, hinb);
    scan_passC<<<dim3(NC, Bb * Kd4), 512, 0, stream>>>(xdbl, x1p, x2p, p.dtw, p.dtb, p.al,
                                                       p.dsk, hinb, ysA);
    combine_ln<<<dim3(Ll, Bb), 512, 0, stream>>>(ysA, xz, p.lnw, p.lnb, yln);
    gemm_aw<<<dim3(Mrows / 64, Cc / 64), 256, 0, stream>>>(yln, DI, p.ow, DI, outp, Cc,
                                                           Mrows, Cc, DI, act);
}

extern "C" void kernel_launch(void* const* d_in, const int* in_sizes, int n_in,
                              void* d_out, int out_size, void* d_ws, size_t ws_size,
                              hipStream_t stream)
{
    // --- input mapping: setup_inputs() dict order, with a fallback to
    //     function-arg order (distinguished by in_sizes[3]).
    // dict order:  x,replk_w,replk_b,qkv_w,q_w,q_b,k_w,k_b,dwc_w,dwc_b,
    //              cbr_w,cbr_g,cbr_b, s1_(11), s2_(11)
    // arg order:   x,replk_w,replk_b, s1_(11), qkv_w,q_w..cbr_b, s2_(11)
    int i_x, i_rw, i_rb, i_qkv, i_qw, i_qb, i_kw, i_kb, i_dw, i_db, i_cw, i_cg, i_cb2, s1b, s2b;
    if (in_sizes[3] == 3 * 256 * 256) {   // qkv_w at index 3 -> dict order
        i_x = 0; i_rw = 1; i_rb = 2; i_qkv = 3; i_qw = 4; i_qb = 5; i_kw = 6; i_kb = 7;
        i_dw = 8; i_db = 9; i_cw = 10; i_cg = 11; i_cb2 = 12; s1b = 13; s2b = 24;
    } else {                               // s1_in_w at index 3 -> arg order
        i_x = 0; i_rw = 1; i_rb = 2; s1b = 3; i_qkv = 14; i_qw = 15; i_qb = 16; i_kw = 17;
        i_kb = 18; i_dw = 19; i_db = 20; i_cw = 21; i_cg = 22; i_cb2 = 23; s2b = 24;
    }
    auto F = [&](int i) { return (const float*)d_in[i]; };
    const float* x      = F(i_x);
    const float* replkw = F(i_rw);
    const float* replkb = F(i_rb);
    const float* qkvw   = F(i_qkv);
    const float* qw     = F(i_qw);
    const float* qb     = F(i_qb);
    const float* kw     = F(i_kw);
    const float* kb     = F(i_kb);
    const float* dww    = F(i_dw);
    const float* dwb    = F(i_db);
    const float* cbrw   = F(i_cw);
    const float* cbrg   = F(i_cg);
    const float* cbrb   = F(i_cb2);
    SSParams s1 { F(s1b+0), F(s1b+1), F(s1b+2), F(s1b+3), F(s1b+4), F(s1b+5),
                  F(s1b+6), F(s1b+7), F(s1b+8), F(s1b+9), F(s1b+10) };
    SSParams s2 { F(s2b+0), F(s2b+1), F(s2b+2), F(s2b+3), F(s2b+4), F(s2b+5),
                  F(s2b+6), F(s2b+7), F(s2b+8), F(s2b+9), F(s2b+10) };

    // --- workspace carve-up (floats)
    float* ws = (float*)d_ws;
    size_t off = 0;
    auto alloc = [&](size_t n) { float* p = ws + off; off += n; return p; };
    float* xT   = alloc((size_t)Bb * Ll * Cc);
    float* yrep = alloc((size_t)Bb * Ll * Cc);
    float* xz   = alloc((size_t)Bb * Ll * 1024);
    float* x1p  = alloc((size_t)Bb * Ll * DI);
    float* x2p  = alloc((size_t)Bb * Ll * DI);
    float* xdbl = alloc((size_t)Bb * Kd4 * Ll * 48);
    float* Pb   = alloc((size_t)Bb * Kd4 * NC * NS * DI);
    float* Qb   = alloc((size_t)Bb * Kd4 * NC * NS * DI);
    float* hinb = alloc((size_t)Bb * Kd4 * NC * NS * DI);
    float* ysA  = alloc((size_t)Bb * Kd4 * Ll * DI);
    float* yln  = alloc((size_t)Bb * Ll * DI);
    float* s1o  = alloc((size_t)Bb * Ll * Cc);
    float* qkvb = alloc((size_t)Bb * Ll * 768);
    float* sbuf = alloc((size_t)Bb * Ll * Cc);
    float* gbuf = alloc((size_t)Bb * Ll * Cc);
    float* y2b  = alloc((size_t)Bb * Ll * Cc);
    float* mbuf = alloc((size_t)Bb * Cc);
    float* y1b  = alloc((size_t)Bb * Cc);
    (void)ws_size; (void)n_in; (void)out_size;

    const int Mrows = Bb * Ll;

    // 1. x -> pixel-major
    transpose_in<<<dim3(Ll / 32, Cc / 32, Bb), 256, 0, stream>>>(x, xT);
    // 2. 13x13 depthwise
    dwconv13<<<dim3(Ll, Bb), 256, 0, stream>>>(xT, replkw, replkb, yrep);
    // 3. SS2D #1 (with clip(0,6) epilogue)
    run_ss2d(yrep, s1, s1o, 1, xz, x1p, x2p, xdbl, Pb, Qb, hinb, ysA, yln, stream);
    // 4. qkv projection
    gemm_aw<<<dim3(Mrows / 64, 768 / 64), 256, 0, stream>>>(s1o, Cc, qkvw, Cc, qkvb, 768,
                                                            Mrows, 768, Cc, 0);
    // 5. q/k depthwise + sum
    conv_qk<<<dim3(Ll, Bb), 256, 0, stream>>>(qkvb, qw, qb, kw, kb, sbuf);
    // 6. g = dw3(q+k) * v
    conv_g<<<dim3(Ll, Bb), 256, 0, stream>>>(sbuf, dww, dwb, qkvb, gbuf);
    // 7. channel attention branch
    hipMemsetAsync(mbuf, 0, (size_t)Bb * Cc * sizeof(float), stream);
    reduce_mean<<<dim3(Ll / 128, Bb), 256, 0, stream>>>(gbuf, mbuf);
    cbr_kernel<<<dim3(Bb), 256, 0, stream>>>(mbuf, cbrw, cbrg, cbrb, y1b);
    // 8. SS2D #2
    run_ss2d(gbuf, s2, y2b, 0, xz, x1p, x2p, xdbl, Pb, Qb, hinb, ysA, yln, stream);
    // 9. out = g * (y1 + y2), transposed to channel-major
    final_kernel<<<dim3(Ll / 32, Cc / 32, Bb), 256, 0, stream>>>(gbuf, y1b, y2b, (float*)d_out);
}

// Round 4
// 835.942 us; speedup vs baseline: 1.6966x; 1.6966x over previous
//
#include <hip/hip_runtime.h>
#include <hip/hip_bf16.h>
#include <math.h>

// ---------------------------------------------------------------------------
// AdditiveTokenMixer (VMamba-ish): full fp32 implementation.
// B=2, C=256, H=W=48, L=2304, DI=512, NS=DR=16, K=4 directions.
// Layout convention: all activations pixel-major [b, l, ch] (coalesced over ch).
// Scan: chunked linear recurrence (48 chunks x 48 steps, 3 passes).
// R4: dwconv13 rewritten channel-major with LDS-staged 60x60 padded image
//     (was latency-bound at 640us, VALUBusy 1.7%); input transpose now runs
//     AFTER the conv (x is already channel-major).
// ---------------------------------------------------------------------------

constexpr int Bb  = 2;
constexpr int Cc  = 256;
constexpr int Hh  = 48;
constexpr int Wd  = 48;
constexpr int Ll  = Hh * Wd;     // 2304
constexpr int DI  = 512;
constexpr int NS  = 16;
constexpr int DR  = 16;
constexpr int Kd4 = 4;
constexpr int NC  = 48;          // number of chunks
constexpr int CL  = 48;          // chunk length (NC*CL == Ll)

#define DEV __device__ __forceinline__

DEV float sigmoidf_(float x) { return 1.0f / (1.0f + __expf(-x)); }
DEV float siluf_(float x)    { return x * sigmoidf_(x); }
DEV float softplusf_(float x){ return fmaxf(x, 0.0f) + log1pf(__expf(-fabsf(x))); }

// ---------------------------------------------------------------------------
// Transpose [b, c, l] -> [b, l, c]   (tile 32x32 via LDS)
// grid (Ll/32, Cc/32, Bb), block 256
// ---------------------------------------------------------------------------
__global__ __launch_bounds__(256) void transpose_in(const float* __restrict__ x,
                                                    float* __restrict__ xT)
{
    __shared__ float tile[32][33];
    int l0 = blockIdx.x * 32, c0 = blockIdx.y * 32, b = blockIdx.z;
    int t = threadIdx.x;
    int li = t & 31, ci = t >> 5;           // ci 0..7
#pragma unroll
    for (int i = 0; i < 4; i++) {
        int cc = ci + i * 8;
        tile[cc][li] = x[((size_t)b * Cc + c0 + cc) * Ll + l0 + li];
    }
    __syncthreads();
#pragma unroll
    for (int i = 0; i < 4; i++) {
        int ll = ci + i * 8;
        xT[((size_t)b * Ll + l0 + ll) * Cc + c0 + li] = tile[li][ll];
    }
}

// ---------------------------------------------------------------------------
// 13x13 depthwise conv, pad 6, CHANNEL-MAJOR: in x[b,c,48,48] -> out[b,c,48,48].
// One block per (c, b); full zero-padded 60x60 image in LDS; branch-free
// fully-unrolled taps. grid (Cc, Bb), block 256 (9 pixels/thread).
// ---------------------------------------------------------------------------
__global__ __launch_bounds__(256) void dwconv13_cm(const float* __restrict__ x,
                                                   const float* __restrict__ wgt,
                                                   const float* __restrict__ bias,
                                                   float* __restrict__ out)
{
    __shared__ float img[60 * 60];
    __shared__ float wsh[169];
    int c = blockIdx.x, b = blockIdx.y;
    int t = threadIdx.x;
    for (int i = t; i < 3600; i += 256) img[i] = 0.0f;
    if (t < 169) wsh[t] = wgt[(size_t)c * 169 + t];
    __syncthreads();
    const float* src = x + ((size_t)b * Cc + c) * Ll;
    for (int i = t; i < Ll; i += 256) {
        int h = i / 48, w = i - h * 48;
        img[(h + 6) * 60 + (w + 6)] = src[i];
    }
    __syncthreads();
    float bs = bias[c];
    float acc[9];
    int base[9];
#pragma unroll
    for (int k = 0; k < 9; k++) {
        acc[k] = bs;
        int l = t + k * 256;
        int h = l / 48, w = l - h * 48;
        base[k] = h * 60 + w;      // top-left tap of the 13x13 window in img
    }
    for (int ky = 0; ky < 13; ky++) {
#pragma unroll
        for (int kx = 0; kx < 13; kx++) {
            float wv = wsh[ky * 13 + kx];
#pragma unroll
            for (int k = 0; k < 9; k++)
                acc[k] = fmaf(img[base[k] + ky * 60 + kx], wv, acc[k]);
        }
    }
    float* dst = out + ((size_t)b * Cc + c) * Ll;
#pragma unroll
    for (int k = 0; k < 9; k++)
        dst[t + k * 256] = acc[k];
}

// ---------------------------------------------------------------------------
// Generic fp32 GEMM: C[m,n] = sum_k A[m,k]*W[n,k]; M%64==0, N%64==0, K%16==0.
// act: 0 none, 1 clip(0,6).  block 256, tile 64x64x16, 4x4 per thread.
// ---------------------------------------------------------------------------
__global__ __launch_bounds__(256) void gemm_aw(const float* __restrict__ A, int lda,
                                               const float* __restrict__ W, int ldw,
                                               float* __restrict__ C, int ldc,
                                               int M, int N, int Kdim, int act)
{
    __shared__ float As[16][68];
    __shared__ float Ws[16][68];
    int bm = blockIdx.x * 64, bn = blockIdx.y * 64;
    int t = threadIdx.x;
    int lm = t >> 2;             // 0..63
    int lk = (t & 3) * 4;        // 0,4,8,12
    int tn = (t & 15) * 4, tm = (t >> 4) * 4;
    float acc[4][4] = {};
    for (int k0 = 0; k0 < Kdim; k0 += 16) {
        float4 av = *(const float4*)(A + (size_t)(bm + lm) * lda + k0 + lk);
        float4 wv = *(const float4*)(W + (size_t)(bn + lm) * ldw + k0 + lk);
        As[lk + 0][lm] = av.x; As[lk + 1][lm] = av.y; As[lk + 2][lm] = av.z; As[lk + 3][lm] = av.w;
        Ws[lk + 0][lm] = wv.x; Ws[lk + 1][lm] = wv.y; Ws[lk + 2][lm] = wv.z; Ws[lk + 3][lm] = wv.w;
        __syncthreads();
#pragma unroll
        for (int kk = 0; kk < 16; kk++) {
            float a[4], w4[4];
#pragma unroll
            for (int i = 0; i < 4; i++) a[i] = As[kk][tm + i];
#pragma unroll
            for (int j = 0; j < 4; j++) w4[j] = Ws[kk][tn + j];
#pragma unroll
            for (int i = 0; i < 4; i++)
#pragma unroll
                for (int j = 0; j < 4; j++)
                    acc[i][j] = fmaf(a[i], w4[j], acc[i][j]);
        }
        __syncthreads();
    }
#pragma unroll
    for (int i = 0; i < 4; i++)
#pragma unroll
        for (int j = 0; j < 4; j++) {
            float v = acc[i][j];
            if (act == 1) v = fminf(fmaxf(v, 0.0f), 6.0f);
            C[(size_t)(bm + tm + i) * ldc + bn + tn + j] = v;
        }
}

// ---------------------------------------------------------------------------
// dw3x3 + SiLU on xi (cols 0..511 of xz [b,l,1024]); writes x1 (hw order) and
// x2 (wh order), both [b,l,512].  grid (Ll, Bb), block 512
// ---------------------------------------------------------------------------
__global__ __launch_bounds__(512) void conv3_silu_dual(const float* __restrict__ xz,
                                                       const float* __restrict__ cw,
                                                       const float* __restrict__ cb,
                                                       float* __restrict__ x1p,
                                                       float* __restrict__ x2p)
{
    __shared__ float wsm[DI * 9];
    int l = blockIdx.x, b = blockIdx.y;
    int h = l / Wd, w = l % Wd, d = threadIdx.x;
    for (int i = d; i < DI * 9; i += 512) wsm[i] = cw[i];
    __syncthreads();
    float acc = cb[d];
    const float* wp = wsm + d * 9;
#pragma unroll
    for (int ky = 0; ky < 3; ky++) {
        int y = h + ky - 1;
        if ((unsigned)y >= (unsigned)Hh) continue;
#pragma unroll
        for (int kx = 0; kx < 3; kx++) {
            int xx = w + kx - 1;
            if ((unsigned)xx >= (unsigned)Wd) continue;
            acc = fmaf(xz[((size_t)b * Ll + y * Wd + xx) * 1024 + d], wp[ky * 3 + kx], acc);
        }
    }
    float s = siluf_(acc);
    x1p[((size_t)b * Ll + l) * DI + d] = s;
    x2p[((size_t)b * Ll + (w * Hh + h)) * DI + d] = s;
}

// ---------------------------------------------------------------------------
// x_dbl GEMM: for z=(b*4+k): C[l, c(48)] = sum_d xbase_k[b,l,d] * xp[k,c,d]
// grid (Ll/64, 1, 8), block 256; tile 64x48x16, 4x3 per thread
// ---------------------------------------------------------------------------
__global__ __launch_bounds__(256) void gemm_xdbl(const float* __restrict__ x1p,
                                                 const float* __restrict__ x2p,
                                                 const float* __restrict__ xp,
                                                 float* __restrict__ xdbl)
{
    __shared__ float As[16][68];
    __shared__ float Ws[16][52];
    int z = blockIdx.z;
    int b = z >> 2, k = z & 3;
    const float* A = ((k & 1) ? x2p : x1p) + (size_t)b * Ll * DI;
    const float* W = xp + (size_t)k * 48 * DI;
    float* C = xdbl + (size_t)z * Ll * 48;
    int bm = blockIdx.x * 64;
    int t = threadIdx.x;
    int lm = t >> 2, lk = (t & 3) * 4;
    int tn = (t & 15) * 3, tm = (t >> 4) * 4;
    float acc[4][3] = {};
    for (int k0 = 0; k0 < DI; k0 += 16) {
        float4 av = *(const float4*)(A + (size_t)(bm + lm) * DI + k0 + lk);
        As[lk + 0][lm] = av.x; As[lk + 1][lm] = av.y; As[lk + 2][lm] = av.z; As[lk + 3][lm] = av.w;
        if (t < 192) {
            int wn = t >> 2;   // 0..47
            float4 wv = *(const float4*)(W + (size_t)wn * DI + k0 + lk);
            Ws[lk + 0][wn] = wv.x; Ws[lk + 1][wn] = wv.y; Ws[lk + 2][wn] = wv.z; Ws[lk + 3][wn] = wv.w;
        }
        __syncthreads();
#pragma unroll
        for (int kk = 0; kk < 16; kk++) {
            float a[4], w4[3];
#pragma unroll
            for (int i = 0; i < 4; i++) a[i] = As[kk][tm + i];
#pragma unroll
            for (int j = 0; j < 3; j++) w4[j] = Ws[kk][tn + j];
#pragma unroll
            for (int i = 0; i < 4; i++)
#pragma unroll
                for (int j = 0; j < 3; j++)
                    acc[i][j] = fmaf(a[i], w4[j], acc[i][j]);
        }
        __syncthreads();
    }
#pragma unroll
    for (int i = 0; i < 4; i++)
#pragma unroll
        for (int j = 0; j < 3; j++)
            C[(size_t)(bm + tm + i) * 48 + tn + j] = acc[i][j];
}

// ---------------------------------------------------------------------------
// Scan pass A: per (chunk, b, k, d) compute chunk summary (P,Q):
//   h_end = P*h_in + Q  for each of 16 states.
// grid (NC, Bb*Kd4), block 512 (=d)
// ---------------------------------------------------------------------------
__global__ __launch_bounds__(512) void scan_passA(const float* __restrict__ xdbl,
                                                  const float* __restrict__ x1p,
                                                  const float* __restrict__ x2p,
                                                  const float* __restrict__ dtw,
                                                  const float* __restrict__ dtb,
                                                  const float* __restrict__ al,
                                                  float* __restrict__ P,
                                                  float* __restrict__ Q)
{
    __shared__ __align__(16) float xds[CL * 48];
    int chunk = blockIdx.x;
    int bk = blockIdx.y;
    int b = bk >> 2, k = bk & 3;
    int d = threadIdx.x;
    int rowbase = (k < 2) ? chunk * CL : (Ll - CL * (chunk + 1));
    const float* src = xdbl + ((size_t)bk * Ll + rowbase) * 48;
    for (int i = d; i < CL * 48; i += 512) xds[i] = src[i];

    float w_dt[16], Aa[16];
    const float* dtwp = dtw + ((size_t)k * DI + d) * DR;
    const float* alp  = al  + ((size_t)k * DI + d) * NS;
#pragma unroll
    for (int n = 0; n < 16; n++) { w_dt[n] = dtwp[n]; Aa[n] = -__expf(alp[n]); }
    float dtb_s = dtb[k * DI + d];
    const float* xb = ((k & 1) ? x2p : x1p) + (size_t)b * Ll * DI + d;

    float Pr[16], Qr[16];
#pragma unroll
    for (int n = 0; n < 16; n++) { Pr[n] = 1.0f; Qr[n] = 0.0f; }
    __syncthreads();

    for (int tl = 0; tl < CL; tl++) {
        int tglob = chunk * CL + tl;
        int p  = (k < 2) ? tglob : (Ll - 1 - tglob);
        int rl = (k < 2) ? tl : (CL - 1 - tl);
        float xv[32];
        {
            const float4* xr4 = reinterpret_cast<const float4*>(&xds[rl * 48]);
#pragma unroll
            for (int i = 0; i < 8; i++) {
                float4 q = xr4[i];
                xv[4 * i + 0] = q.x; xv[4 * i + 1] = q.y; xv[4 * i + 2] = q.z; xv[4 * i + 3] = q.w;
            }
        }
        float u = xb[(size_t)p * DI];
        float dt = dtb_s;
#pragma unroll
        for (int r = 0; r < 16; r++) dt = fmaf(w_dt[r], xv[r], dt);
        dt = softplusf_(dt);
        float du = dt * u;
#pragma unroll
        for (int n = 0; n < 16; n++) {
            float a = __expf(dt * Aa[n]);
            Pr[n] *= a;
            Qr[n] = fmaf(a, Qr[n], du * xv[16 + n]);
        }
    }
    size_t obase = ((size_t)bk * NC + chunk) * NS * DI + d;
#pragma unroll
    for (int n = 0; n < 16; n++) {
        P[obase + (size_t)n * DI] = Pr[n];
        Q[obase + (size_t)n * DI] = Qr[n];
    }
}

// ---------------------------------------------------------------------------
// Scan pass B: sequential scan over chunk summaries -> h_in per chunk.
// flat threads over (bk, n, d); grid 128 x block 512
// ---------------------------------------------------------------------------
__global__ __launch_bounds__(512) void scan_passB(const float* __restrict__ P,
                                                  const float* __restrict__ Q,
                                                  float* __restrict__ hin)
{
    int gid = blockIdx.x * 512 + threadIdx.x;
    int d = gid & (DI - 1);
    int n = (gid >> 9) & 15;
    int bk = gid >> 13;
    float h = 0.0f;
    for (int c = 0; c < NC; c++) {
        size_t idx = (((size_t)bk * NC + c) * NS + n) * DI + d;
        hin[idx] = h;
        h = fmaf(P[idx], h, Q[idx]);
    }
}

// ---------------------------------------------------------------------------
// Scan pass C: replay each chunk with known h_in, emit ys (+ D skip).
// ys stored source-pixel-indexed: ysA[(bk*L + p)*DI + d]
// ---------------------------------------------------------------------------
__global__ __launch_bounds__(512) void scan_passC(const float* __restrict__ xdbl,
                                                  const float* __restrict__ x1p,
                                                  const float* __restrict__ x2p,
                                                  const float* __restrict__ dtw,
                                                  const float* __restrict__ dtb,
                                                  const float* __restrict__ al,
                                                  const float* __restrict__ dsk,
                                                  const float* __restrict__ hin,
                                                  float* __restrict__ ysA)
{
    __shared__ __align__(16) float xds[CL * 48];
    int chunk = blockIdx.x;
    int bk = blockIdx.y;
    int b = bk >> 2, k = bk & 3;
    int d = threadIdx.x;
    int rowbase = (k < 2) ? chunk * CL : (Ll - CL * (chunk + 1));
    const float* src = xdbl + ((size_t)bk * Ll + rowbase) * 48;
    for (int i = d; i < CL * 48; i += 512) xds[i] = src[i];

    float w_dt[16], Aa[16], hreg[16];
    const float* dtwp = dtw + ((size_t)k * DI + d) * DR;
    const float* alp  = al  + ((size_t)k * DI + d) * NS;
#pragma unroll
    for (int n = 0; n < 16; n++) { w_dt[n] = dtwp[n]; Aa[n] = -__expf(alp[n]); }
    float dtb_s = dtb[k * DI + d];
    float dp_s  = dsk[k * DI + d];
    size_t hbase = ((size_t)bk * NC + chunk) * NS * DI + d;
#pragma unroll
    for (int n = 0; n < 16; n++) hreg[n] = hin[hbase + (size_t)n * DI];
    const float* xb = ((k & 1) ? x2p : x1p) + (size_t)b * Ll * DI + d;
    __syncthreads();

    for (int tl = 0; tl < CL; tl++) {
        int tglob = chunk * CL + tl;
        int p  = (k < 2) ? tglob : (Ll - 1 - tglob);
        int rl = (k < 2) ? tl : (CL - 1 - tl);
        float xv[48];
        {
            const float4* xr4 = reinterpret_cast<const float4*>(&xds[rl * 48]);
#pragma unroll
            for (int i = 0; i < 12; i++) {
                float4 q = xr4[i];
                xv[4 * i + 0] = q.x; xv[4 * i + 1] = q.y; xv[4 * i + 2] = q.z; xv[4 * i + 3] = q.w;
            }
        }
        float u = xb[(size_t)p * DI];
        float dt = dtb_s;
#pragma unroll
        for (int r = 0; r < 16; r++) dt = fmaf(w_dt[r], xv[r], dt);
        dt = softplusf_(dt);
        float du = dt * u;
        float y = 0.0f;
#pragma unroll
        for (int n = 0; n < 16; n++) {
            float a = __expf(dt * Aa[n]);
            hreg[n] = fmaf(a, hreg[n], du * xv[16 + n]);
            y = fmaf(hreg[n], xv[32 + n], y);
        }
        y = fmaf(dp_s, u, y);
        ysA[((size_t)bk * Ll + p) * DI + d] = y;
    }
}

// ---------------------------------------------------------------------------
// Combine 4 directions + LayerNorm(512) + SiLU(z) gate -> yln [b,l,512]
// grid (Ll, Bb), block 512
// ---------------------------------------------------------------------------
__global__ __launch_bounds__(512) void combine_ln(const float* __restrict__ ysA,
                                                  const float* __restrict__ xz,
                                                  const float* __restrict__ lnw,
                                                  const float* __restrict__ lnb,
                                                  float* __restrict__ yln)
{
    __shared__ float red[16];
    int l = blockIdx.x, b = blockIdx.y;
    int h = l / Wd, w = l % Wd;
    int wh = w * Hh + h;
    int d = threadIdx.x;
    size_t k0 = ((size_t)(b * 4 + 0) * Ll + l)  * DI + d;
    size_t k1 = ((size_t)(b * 4 + 1) * Ll + wh) * DI + d;
    size_t k2 = ((size_t)(b * 4 + 2) * Ll + l)  * DI + d;
    size_t k3 = ((size_t)(b * 4 + 3) * Ll + wh) * DI + d;
    float v = ysA[k0] + ysA[k1] + ysA[k2] + ysA[k3];

    float s = v, s2 = v * v;
#pragma unroll
    for (int off = 32; off > 0; off >>= 1) {
        s  += __shfl_down(s, off);
        s2 += __shfl_down(s2, off);
    }
    int wid = d >> 6, lane = d & 63;
    if (lane == 0) { red[wid] = s; red[8 + wid] = s2; }
    __syncthreads();
    if (d == 0) {
        float ts = 0.0f, ts2 = 0.0f;
        for (int i = 0; i < 8; i++) { ts += red[i]; ts2 += red[8 + i]; }
        red[0] = ts * (1.0f / DI);
        red[1] = ts2 * (1.0f / DI);
    }
    __syncthreads();
    float mu = red[0];
    float var = red[1] - mu * mu;
    float yn = (v - mu) * rsqrtf(var + 1e-5f) * lnw[d] + lnb[d];
    float zv = xz[((size_t)b * Ll + l) * 1024 + DI + d];
    yn *= siluf_(zv);
    yln[((size_t)b * Ll + l) * DI + d] = yn;
}

// ---------------------------------------------------------------------------
// conv_qk: qc = dw3(q)+qb, kc = dw3(k)+kb, sbuf = qc+kc   [b,l,256]
// ---------------------------------------------------------------------------
__global__ __launch_bounds__(256) void conv_qk(const float* __restrict__ qkv,
                                               const float* __restrict__ qw,
                                               const float* __restrict__ qb,
                                               const float* __restrict__ kw,
                                               const float* __restrict__ kb,
                                               float* __restrict__ sbuf)
{
    __shared__ float wq[Cc * 9], wk[Cc * 9];
    int l = blockIdx.x, b = blockIdx.y;
    int h = l / Wd, w = l % Wd, c = threadIdx.x;
    for (int i = c; i < Cc * 9; i += 256) { wq[i] = qw[i]; wk[i] = kw[i]; }
    __syncthreads();
    float aq = qb[c], ak = kb[c];
#pragma unroll
    for (int ky = 0; ky < 3; ky++) {
        int y = h + ky - 1;
        if ((unsigned)y >= (unsigned)Hh) continue;
#pragma unroll
        for (int kx = 0; kx < 3; kx++) {
            int xx = w + kx - 1;
            if ((unsigned)xx >= (unsigned)Wd) continue;
            size_t base = ((size_t)b * Ll + y * Wd + xx) * 768;
            aq = fmaf(qkv[base + c],       wq[c * 9 + ky * 3 + kx], aq);
            ak = fmaf(qkv[base + Cc + c],  wk[c * 9 + ky * 3 + kx], ak);
        }
    }
    sbuf[((size_t)b * Ll + l) * Cc + c] = aq + ak;
}

// ---------------------------------------------------------------------------
// conv_g: g = (dw3(sbuf)+db) * v     [b,l,256]
// ---------------------------------------------------------------------------
__global__ __launch_bounds__(256) void conv_g(const float* __restrict__ sbuf,
                                              const float* __restrict__ dw,
                                              const float* __restrict__ db,
                                              const float* __restrict__ qkv,
                                              float* __restrict__ g)
{
    __shared__ float wsm[Cc * 9];
    int l = blockIdx.x, b = blockIdx.y;
    int h = l / Wd, w = l % Wd, c = threadIdx.x;
    for (int i = c; i < Cc * 9; i += 256) wsm[i] = dw[i];
    __syncthreads();
    float acc = db[c];
#pragma unroll
    for (int ky = 0; ky < 3; ky++) {
        int y = h + ky - 1;
        if ((unsigned)y >= (unsigned)Hh) continue;
#pragma unroll
        for (int kx = 0; kx < 3; kx++) {
            int xx = w + kx - 1;
            if ((unsigned)xx >= (unsigned)Wd) continue;
            acc = fmaf(sbuf[((size_t)b * Ll + y * Wd + xx) * Cc + c], wsm[c * 9 + ky * 3 + kx], acc);
        }
    }
    float v = qkv[((size_t)b * Ll + l) * 768 + 2 * Cc + c];
    g[((size_t)b * Ll + l) * Cc + c] = acc * v;
}

// ---------------------------------------------------------------------------
// reduce_mean: partial sums of g over pixels (atomic accumulate)
// grid (18, Bb) block 256; each block sums 128 pixels
// ---------------------------------------------------------------------------
__global__ __launch_bounds__(256) void reduce_mean(const float* __restrict__ g,
                                                   float* __restrict__ m)
{
    int b = blockIdx.y, c = threadIdx.x;
    int l0 = blockIdx.x * 128;
    float s = 0.0f;
    for (int i = 0; i < 128; i++)
        s += g[((size_t)b * Ll + l0 + i) * Cc + c];
    atomicAdd(&m[b * Cc + c], s);
}

// ---------------------------------------------------------------------------
// cbr: y1[b,o] = relu( (sum_c mean_g[c]*w[o,c]) * gain[o] + bias[o] )
// ---------------------------------------------------------------------------
__global__ __launch_bounds__(256) void cbr_kernel(const float* __restrict__ m,
                                                  const float* __restrict__ wgt,
                                                  const float* __restrict__ gain,
                                                  const float* __restrict__ bias,
                                                  float* __restrict__ y1)
{
    __shared__ float ms[Cc];
    int b = blockIdx.x, o = threadIdx.x;
    ms[o] = m[b * Cc + o] * (1.0f / (float)Ll);
    __syncthreads();
    float t = 0.0f;
    for (int c = 0; c < Cc; c++) t = fmaf(ms[c], wgt[(size_t)o * Cc + c], t);
    float v = t * gain[o] + bias[o];
    y1[b * Cc + o] = fmaxf(v, 0.0f);
}

// ---------------------------------------------------------------------------
// final: out[b,o,l] = g[b,l,o] * (y1[b,o] + y2[b,l,o])   (transpose via LDS)
// grid (Ll/32, Cc/32, Bb), block 256
// ---------------------------------------------------------------------------
__global__ __launch_bounds__(256) void final_kernel(const float* __restrict__ g,
                                                    const float* __restrict__ y1,
                                                    const float* __restrict__ y2,
                                                    float* __restrict__ out)
{
    __shared__ float tile[32][33];
    int l0 = blockIdx.x * 32, o0 = blockIdx.y * 32, b = blockIdx.z;
    int t = threadIdx.x;
    int lo = t & 31, li = t >> 5;
#pragma unroll
    for (int i = 0; i < 4; i++) {
        int ll = li + i * 8;
        size_t idx = ((size_t)b * Ll + l0 + ll) * Cc + o0 + lo;
        tile[ll][lo] = g[idx] * (y1[b * Cc + o0 + lo] + y2[idx]);
    }
    __syncthreads();
#pragma unroll
    for (int i = 0; i < 4; i++) {
        int oo = li + i * 8;
        out[((size_t)b * Cc + o0 + oo) * Ll + l0 + lo] = tile[lo][oo];
    }
}

// ---------------------------------------------------------------------------
// Host side
// ---------------------------------------------------------------------------
struct SSParams {
    const float *in_w, *cw, *cb, *xp, *dtw, *dtb, *al, *dsk, *lnw, *lnb, *ow;
};

static void run_ss2d(const float* inp, const SSParams& p, float* outp, int act,
                     float* xz, float* x1p, float* x2p, float* xdbl,
                     float* Pb, float* Qb, float* hinb, float* ysA, float* yln,
                     hipStream_t stream)
{
    const int Mrows = Bb * Ll;   // 4608
    gemm_aw<<<dim3(Mrows / 64, 1024 / 64), 256, 0, stream>>>(inp, Cc, p.in_w, Cc, xz, 1024,
                                                             Mrows, 1024, Cc, 0);
    conv3_silu_dual<<<dim3(Ll, Bb), 512, 0, stream>>>(xz, p.cw, p.cb, x1p, x2p);
    gemm_xdbl<<<dim3(Ll / 64, 1, Bb * Kd4), 256, 0, stream>>>(x1p, x2p, p.xp, xdbl);
    scan_passA<<<dim3(NC, Bb * Kd4), 512, 0, stream>>>(xdbl, x1p, x2p, p.dtw, p.dtb, p.al, Pb, Qb);
    scan_passB<<<dim3((Bb * Kd4 * NS * DI) / 512), 512, 0, stream>>>(Pb, Qb, hinb);
    scan_passC<<<dim3(NC, Bb * Kd4), 512, 0, stream>>>(xdbl, x1p, x2p, p.dtw, p.dtb, p.al,
                                                       p.dsk, hinb, ysA);
    combine_ln<<<dim3(Ll, Bb), 512, 0, stream>>>(ysA, xz, p.lnw, p.lnb, yln);
    gemm_aw<<<dim3(Mrows / 64, Cc / 64), 256, 0, stream>>>(yln, DI, p.ow, DI, outp, Cc,
                                                           Mrows, Cc, DI, act);
}

extern "C" void kernel_launch(void* const* d_in, const int* in_sizes, int n_in,
                              void* d_out, int out_size, void* d_ws, size_t ws_size,
                              hipStream_t stream)
{
    // --- input mapping: setup_inputs() dict order, with a fallback to
    //     function-arg order (distinguished by in_sizes[3]).
    int i_x, i_rw, i_rb, i_qkv, i_qw, i_qb, i_kw, i_kb, i_dw, i_db, i_cw, i_cg, i_cb2, s1b, s2b;
    if (in_sizes[3] == 3 * 256 * 256) {   // qkv_w at index 3 -> dict order
        i_x = 0; i_rw = 1; i_rb = 2; i_qkv = 3; i_qw = 4; i_qb = 5; i_kw = 6; i_kb = 7;
        i_dw = 8; i_db = 9; i_cw = 10; i_cg = 11; i_cb2 = 12; s1b = 13; s2b = 24;
    } else {                               // s1_in_w at index 3 -> arg order
        i_x = 0; i_rw = 1; i_rb = 2; s1b = 3; i_qkv = 14; i_qw = 15; i_qb = 16; i_kw = 17;
        i_kb = 18; i_dw = 19; i_db = 20; i_cw = 21; i_cg = 22; i_cb2 = 23; s2b = 24;
    }
    auto F = [&](int i) { return (const float*)d_in[i]; };
    const float* x      = F(i_x);
    const float* replkw = F(i_rw);
    const float* replkb = F(i_rb);
    const float* qkvw   = F(i_qkv);
    const float* qw     = F(i_qw);
    const float* qb     = F(i_qb);
    const float* kw     = F(i_kw);
    const float* kb     = F(i_kb);
    const float* dww    = F(i_dw);
    const float* dwb    = F(i_db);
    const float* cbrw   = F(i_cw);
    const float* cbrg   = F(i_cg);
    const float* cbrb   = F(i_cb2);
    SSParams s1 { F(s1b+0), F(s1b+1), F(s1b+2), F(s1b+3), F(s1b+4), F(s1b+5),
                  F(s1b+6), F(s1b+7), F(s1b+8), F(s1b+9), F(s1b+10) };
    SSParams s2 { F(s2b+0), F(s2b+1), F(s2b+2), F(s2b+3), F(s2b+4), F(s2b+5),
                  F(s2b+6), F(s2b+7), F(s2b+8), F(s2b+9), F(s2b+10) };

    // --- workspace carve-up (floats)
    float* ws = (float*)d_ws;
    size_t off = 0;
    auto alloc = [&](size_t n) { float* p = ws + off; off += n; return p; };
    float* ycm  = alloc((size_t)Bb * Ll * Cc);   // dwconv13 output, channel-major
    float* yrep = alloc((size_t)Bb * Ll * Cc);   // pixel-major
    float* xz   = alloc((size_t)Bb * Ll * 1024);
    float* x1p  = alloc((size_t)Bb * Ll * DI);
    float* x2p  = alloc((size_t)Bb * Ll * DI);
    float* xdbl = alloc((size_t)Bb * Kd4 * Ll * 48);
    float* Pb   = alloc((size_t)Bb * Kd4 * NC * NS * DI);
    float* Qb   = alloc((size_t)Bb * Kd4 * NC * NS * DI);
    float* hinb = alloc((size_t)Bb * Kd4 * NC * NS * DI);
    float* ysA  = alloc((size_t)Bb * Kd4 * Ll * DI);
    float* yln  = alloc((size_t)Bb * Ll * DI);
    float* s1o  = alloc((size_t)Bb * Ll * Cc);
    float* qkvb = alloc((size_t)Bb * Ll * 768);
    float* sbuf = alloc((size_t)Bb * Ll * Cc);
    float* gbuf = alloc((size_t)Bb * Ll * Cc);
    float* y2b  = alloc((size_t)Bb * Ll * Cc);
    float* mbuf = alloc((size_t)Bb * Cc);
    float* y1b  = alloc((size_t)Bb * Cc);
    (void)ws_size; (void)n_in; (void)out_size;

    const int Mrows = Bb * Ll;

    // 1. 13x13 depthwise, channel-major (x is already [b,c,h,w])
    dwconv13_cm<<<dim3(Cc, Bb), 256, 0, stream>>>(x, replkw, replkb, ycm);
    // 2. transpose conv output to pixel-major
    transpose_in<<<dim3(Ll / 32, Cc / 32, Bb), 256, 0, stream>>>(ycm, yrep);
    // 3. SS2D #1 (with clip(0,6) epilogue)
    run_ss2d(yrep, s1, s1o, 1, xz, x1p, x2p, xdbl, Pb, Qb, hinb, ysA, yln, stream);
    // 4. qkv projection
    gemm_aw<<<dim3(Mrows / 64, 768 / 64), 256, 0, stream>>>(s1o, Cc, qkvw, Cc, qkvb, 768,
                                                            Mrows, 768, Cc, 0);
    // 5. q/k depthwise + sum
    conv_qk<<<dim3(Ll, Bb), 256, 0, stream>>>(qkvb, qw, qb, kw, kb, sbuf);
    // 6. g = dw3(q+k) * v
    conv_g<<<dim3(Ll, Bb), 256, 0, stream>>>(sbuf, dww, dwb, qkvb, gbuf);
    // 7. channel attention branch
    hipMemsetAsync(mbuf, 0, (size_t)Bb * Cc * sizeof(float), stream);
    reduce_mean<<<dim3(Ll / 128, Bb), 256, 0, stream>>>(gbuf, mbuf);
    cbr_kernel<<<dim3(Bb), 256, 0, stream>>>(mbuf, cbrw, cbrg, cbrb, y1b);
    // 8. SS2D #2
    run_ss2d(gbuf, s2, y2b, 0, xz, x1p, x2p, xdbl, Pb, Qb, hinb, ysA, yln, stream);
    // 9. out = g * (y1 + y2), transposed to channel-major
    final_kernel<<<dim3(Ll / 32, Cc / 32, Bb), 256, 0, stream>>>(gbuf, y1b, y2b, (float*)d_out);
}